// Round 13
// baseline (279.648 us; speedup 1.0000x reference)
//
#include <hip/hip_runtime.h>
#include <hip/hip_bf16.h>
#include <math.h>

// Problem constants (reference: B=2, S=2048, D=2048, H=16, HD=128)
#define BATCH 2
#define SEQ   2048
#define DIM   2048
#define NH    16
#define HD    128
#define QKV_N (3 * DIM)       // 6144
#define TOKENS (BATCH * SEQ)  // 4096

typedef __attribute__((ext_vector_type(8))) short bf16x8;
typedef __attribute__((ext_vector_type(4))) float f32x4;

typedef __attribute__((address_space(1))) const void* as1cv;
typedef __attribute__((address_space(3))) void* as3v;

__device__ __forceinline__ short f2bf(float x) {
    unsigned u = __float_as_uint(x);
    u += 0x7fffu + ((u >> 16) & 1u);   // round-to-nearest-even (finite inputs)
    return (short)(u >> 16);
}

__device__ __forceinline__ float bf2f(short x) {
    return __uint_as_float(((unsigned)(unsigned short)x) << 16);
}

__device__ __forceinline__ void gload16(const short* g, short* lds) {
    // 16B per lane; LDS dest = wave-uniform base + lane*16 (HW). Source is per-lane.
    __builtin_amdgcn_global_load_lds((as1cv)g, (as3v)lds, 16, 0, 0);
}

// ---------------------------------------------------------------------------
// fp32 -> bf16 elementwise cast (x). Exact-cover grid, 8 elems/thread.
// ---------------------------------------------------------------------------
__global__ __launch_bounds__(256)
void f32_to_bf16_kernel(const float* __restrict__ in, short* __restrict__ out) {
    const size_t i = ((size_t)blockIdx.x * 256 + threadIdx.x) * 8;
    const float4 a = *reinterpret_cast<const float4*>(in + i);
    const float4 b = *reinterpret_cast<const float4*>(in + i + 4);
    bf16x8 v;
    v[0] = f2bf(a.x); v[1] = f2bf(a.y); v[2] = f2bf(a.z); v[3] = f2bf(a.w);
    v[4] = f2bf(b.x); v[5] = f2bf(b.y); v[6] = f2bf(b.z); v[7] = f2bf(b.w);
    *reinterpret_cast<bf16x8*>(out + i) = v;
}

// ---------------------------------------------------------------------------
// fp32 [K][N] -> bf16 [N][K] tiled transpose+cast (weights).
// ---------------------------------------------------------------------------
__global__ __launch_bounds__(256)
void transpose_f32_to_bf16(const float* __restrict__ W, short* __restrict__ Wt,
                           int K, int N) {
    __shared__ float t[64][65];
    const int tid = threadIdx.x;
    const int n0 = blockIdx.x * 64;
    const int k0 = blockIdx.y * 64;
    const int tc = tid & 63, tr = tid >> 6;
    #pragma unroll
    for (int i = 0; i < 16; ++i)
        t[tr + i * 4][tc] = W[(size_t)(k0 + tr + i * 4) * N + n0 + tc];
    __syncthreads();
    #pragma unroll
    for (int i = 0; i < 16; ++i)
        Wt[(size_t)(n0 + tr + i * 4) * K + k0 + tc] = f2bf(t[tc][tr + i * 4]);
}

// ---------------------------------------------------------------------------
// bf16 MFMA GEMM: C[M,N] = A[M,K] @ Bt[N,K]^T + bias[N]
// 128x128 tile, BK=64, 256 threads / 4 waves, double-buffered, counted
// vmcnt(8) (T4) + setprio (T5).
// Round-12/13 reorder: ds_reads are NOT force-drained before the MFMA
// cluster. Per-iter: reads -> MFMA (compiler interleaves via counted
// lgkmcnt) -> s_barrier (reads consumed => complete) -> STAGE(t+2)
// -> vmcnt(8) -> s_barrier. Race-safe: per-wave vmcnt(8)+barrier ensures
// ALL waves' tile-(t+1) loads landed before anyone reads them; ds_reads
// lgkm-retire before their consuming MFMAs issue, so the post-MFMA barrier
// precedes the buffer overwrite safely.
// ---------------------------------------------------------------------------
template <bool BF16OUT>
__global__ __launch_bounds__(256, 2)
void gemm_mfma_kernel(const short* __restrict__ A, const short* __restrict__ Bt,
                      const float* __restrict__ bias, void* __restrict__ Cv,
                      int M, int N, int K, int nM) {
    __shared__ short A_lds[2][128 * 64];   // 2 x 16 KiB
    __shared__ short B_lds[2][128 * 64];   // 2 x 16 KiB

    const int tid  = threadIdx.x;
    const int lane = tid & 63;
    const int w    = tid >> 6;
    const int lr   = lane & 15;
    const int lhi  = lane >> 4;
    const int wr   = w >> 1;
    const int wc   = w & 1;

    const int nwg  = gridDim.x;
    const int cpx  = nwg >> 3;
    const int orig = blockIdx.x;
    const int wg   = (orig & 7) * cpx + (orig >> 3);
    const int bm   = (wg % nM) * 128;
    const int bn   = (wg / nM) * 128;

    const int srow   = tid >> 3;                   // 0..31
    const int schunk = (tid & 7) ^ (srow & 7);     // inverse-swizzled source chunk
    const short* gA = A  + (size_t)(bm + srow) * K + schunk * 8;
    const short* gB = Bt + (size_t)(bn + srow) * K + schunk * 8;

    const int nt = K >> 6;                         // 32 for K=2048

    auto STAGE = [&](int t, int buf) {
        const int ko = t * 64;
        short* la = &A_lds[buf][w * 512];
        short* lb = &B_lds[buf][w * 512];
        #pragma unroll
        for (int i = 0; i < 4; ++i)
            gload16(gA + (size_t)(i * 32) * K + ko, la + i * 2048);
        #pragma unroll
        for (int i = 0; i < 4; ++i)
            gload16(gB + (size_t)(i * 32) * K + ko, lb + i * 2048);
    };

    f32x4 acc[4][4] = {};

    STAGE(0, 0);
    STAGE(1, 1);
    asm volatile("s_waitcnt vmcnt(8)" ::: "memory");   // tile 0 landed
    __builtin_amdgcn_s_barrier();

    int cur = 0;
    for (int t = 0; t < nt; ++t, cur ^= 1) {
        bf16x8 af[2][4], bfr[2][4];
        const short* Ab = &A_lds[cur][0];
        const short* Bb = &B_lds[cur][0];
        #pragma unroll
        for (int ks = 0; ks < 2; ++ks) {
            const int cb = ks * 4 + lhi;
            #pragma unroll
            for (int mi = 0; mi < 4; ++mi) {
                const int r = wr * 64 + mi * 16 + lr;
                af[ks][mi] = *reinterpret_cast<const bf16x8*>(
                    &Ab[r * 64 + ((cb ^ (r & 7)) << 3)]);
            }
            #pragma unroll
            for (int ni = 0; ni < 4; ++ni) {
                const int c = wc * 64 + ni * 16 + lr;
                bfr[ks][ni] = *reinterpret_cast<const bf16x8*>(
                    &Bb[c * 64 + ((cb ^ (c & 7)) << 3)]);
            }
        }
        // no explicit lgkmcnt: compiler interleaves MFMA with counted waits
        __builtin_amdgcn_s_setprio(1);
        #pragma unroll
        for (int ks = 0; ks < 2; ++ks)
            #pragma unroll
            for (int mi = 0; mi < 4; ++mi)
                #pragma unroll
                for (int ni = 0; ni < 4; ++ni)
                    acc[mi][ni] = __builtin_amdgcn_mfma_f32_16x16x32_bf16(
                        af[ks][mi], bfr[ks][ni], acc[mi][ni], 0, 0, 0);
        __builtin_amdgcn_s_setprio(0);

        // reads consumed by MFMA => complete; after barrier buf[cur] is reusable
        __builtin_amdgcn_s_barrier();
        __builtin_amdgcn_sched_barrier(0);      // pin STAGE after the barrier

        if (t + 2 < nt) {
            STAGE(t + 2, cur);
            asm volatile("s_waitcnt vmcnt(8)" ::: "memory");   // t+1 landed
            __builtin_amdgcn_s_barrier();
        } else if (t + 1 < nt) {
            asm volatile("s_waitcnt vmcnt(0)" ::: "memory");   // last tile landed
            __builtin_amdgcn_s_barrier();
        }
    }

    #pragma unroll
    for (int mi = 0; mi < 4; ++mi) {
        #pragma unroll
        for (int j = 0; j < 4; ++j) {
            const int r = bm + wr * 64 + mi * 16 + lhi * 4 + j;
            #pragma unroll
            for (int ni = 0; ni < 4; ++ni) {
                const int c = bn + wc * 64 + ni * 16 + lr;
                const float v = acc[mi][ni][j] + bias[c];
                if (BF16OUT) ((short*)Cv)[(size_t)r * N + c] = f2bf(v);
                else         ((float*)Cv)[(size_t)r * N + c] = v;
            }
        }
    }
}

// ---------------------------------------------------------------------------
// MFMA flash attention (bf16 in/out, fp32 accum). Unchanged from round 11:
// 1024 blocks / 4 waves, gload_lds K, pair-packed V, no-max fused softmax
// (log2-domain prescale, exp2, ones-MFMA row-sum).
// ---------------------------------------------------------------------------
__device__ __forceinline__ int swz8(int row) {   // units: shorts (8 = 16B chunk)
    return ((row ^ (row >> 2)) & 7) << 3;
}

__global__ __launch_bounds__(256)
void attn_mfma_kernel(const short* __restrict__ qkv, short* __restrict__ out) {
    __shared__ short K_lds[64 * 128];    // 16 KiB
    __shared__ short V_lds[128 * 64];    // 16 KiB  (d-major, pair-packed chunks)
    __shared__ short P_lds[4 * 16 * 64]; // 8 KiB   (per-wave P tile)

    const int tid  = threadIdx.x;
    const int lane = tid & 63;
    const int w    = tid >> 6;

    const int z    = blockIdx.x;                 // 0..1023
    const int qblk = (SEQ / 64 - 1) - (z >> 5);  // descending for load balance
    const int bh   = z & 31;
    const int h    = bh & 15;
    const int b    = bh >> 4;

    const int q0 = qblk * 64;
    const size_t tokbase = (size_t)b * SEQ * QKV_N;

    const int lr  = lane & 15;
    const int lhi = lane >> 4;
    // (1/sqrt(128)) * log2(e): QK^T lands in log2 domain, exp2f is 1 instr
    const float lg2scale = 0.1275174468658922f;

    // Q fragments, pre-scaled
    const int qrow = q0 + w * 16 + lr;
    const short* qrowp = qkv + tokbase + (size_t)qrow * QKV_N + h * HD;
    bf16x8 qfrag[4];
    #pragma unroll
    for (int ks = 0; ks < 4; ++ks) {
        bf16x8 v = *reinterpret_cast<const bf16x8*>(qrowp + ks * 32 + lhi * 8);
        bf16x8 sv;
        #pragma unroll
        for (int e = 0; e < 8; ++e) sv[e] = f2bf(bf2f(v[e]) * lg2scale);
        qfrag[ks] = sv;
    }

    // ones B-fragment for the P row-sum MFMA
    bf16x8 ones8;
    #pragma unroll
    for (int e = 0; e < 8; ++e) ones8[e] = (short)0x3F80;   // bf16 1.0

    f32x4 o[8] = {};
    f32x4 lacc = {};                 // l[j] accumulated via ones-MFMA

    const int wq0 = q0 + w * 16;
    const int ntiles = qblk + 1;

    // K staging map: issue i covers rows [i*16, i*16+16)
    const int krow16 = tid >> 4;                 // 0..15 (row within issue group)
    const int kch    = tid & 15;                 // stored 16B chunk 0..15

    for (int t = 0; t < ntiles; ++t) {
        // ---- stage K via global_load_lds (pre-swizzled source, linear dest) ----
        {
            const short* kb = qkv + tokbase + (size_t)(t * 64) * QKV_N + DIM + h * HD;
            #pragma unroll
            for (int i = 0; i < 4; ++i) {
                const int row = i * 16 + krow16;
                const int sch = (kch & 8) | ((kch & 7) ^ ((row ^ (row >> 2)) & 7));
                gload16(kb + (size_t)row * QKV_N + sch * 8,
                        &K_lds[(i * 16 + w * 4) * 128]);
            }
        }
        // ---- stage V (pair-packed b32 scatter, chunk-swizzled) ----
        {
            const int p  = tid >> 3;            // kv pair index 0..31
            const int c  = tid & 7;             // d chunk (16 d each)
            const int kv = p * 2;
            const int kc = kv >> 3;             // kv chunk, per-thread const
            const short* vrow = qkv + tokbase + (size_t)(t * 64 + kv) * QKV_N
                                + 2 * DIM + h * HD + c * 16;
            #pragma unroll
            for (int half = 0; half < 2; ++half) {
                const bf16x8 va = *reinterpret_cast<const bf16x8*>(vrow + half * 8);
                const bf16x8 vb = *reinterpret_cast<const bf16x8*>(vrow + QKV_N + half * 8);
                #pragma unroll
                for (int dd = 0; dd < 8; ++dd) {
                    const int d  = c * 16 + half * 8 + dd;
                    const int sw = ((d >> 4) ^ d) & 7;
                    const unsigned pk = ((unsigned)(unsigned short)va[dd]) |
                                        (((unsigned)(unsigned short)vb[dd]) << 16);
                    *reinterpret_cast<unsigned*>(
                        &V_lds[d * 64 + ((kc ^ sw) << 3) + (kv & 7)]) = pk;
                }
            }
        }
        __syncthreads();   // drains vmcnt (gload_lds) + lgkm; tile visible

        // ---- QK^T (pre-scaled, log2 domain): S[16][64] ----
        f32x4 s[4] = {};
        #pragma unroll
        for (int ks = 0; ks < 4; ++ks) {
            #pragma unroll
            for (int cg = 0; cg < 4; ++cg) {
                const int row = cg * 16 + lr;
                const bf16x8 kf = *reinterpret_cast<const bf16x8*>(
                    &K_lds[row * 128 + ((ks * 32 + lhi * 8) ^ swz8(row))]);
                s[cg] = __builtin_amdgcn_mfma_f32_16x16x32_bf16(qfrag[ks], kf, s[cg], 0, 0, 0);
            }
        }

        // ---- FUSED mask + exp2 + pack (no max, no shuffles; s dies in-loop) ----
        const bool dmask = (t == qblk);
        short* pbase = &P_lds[w * 1024];
        #pragma unroll
        for (int cg = 0; cg < 4; ++cg) {
            const int kvg = t * 64 + cg * 16 + lr;
            const int cx  = cg * 16 + lr;
            #pragma unroll
            for (int j = 0; j < 4; ++j) {
                float sv = s[cg][j];
                if (dmask && (kvg > wq0 + lhi * 4 + j)) sv = -1.0e38f;
                sv = exp2f(fminf(sv, 80.f));
                const int rw = lhi * 4 + j;
                pbase[rw * 64 + (cx ^ swz8(rw))] = f2bf(sv);
            }
        }
        bf16x8 pa[2];
        #pragma unroll
        for (int ks = 0; ks < 2; ++ks)
            pa[ks] = *reinterpret_cast<const bf16x8*>(
                &pbase[lr * 64 + ((ks * 32 + lhi * 8) ^ swz8(lr))]);

        // ---- PV: O[16][128] += P[16][64] . V[64][128] ----
        #pragma unroll
        for (int cg = 0; cg < 8; ++cg) {
            const int d  = cg * 16 + lr;
            const int sw = ((d >> 4) ^ d) & 7;
            #pragma unroll
            for (int ks = 0; ks < 2; ++ks) {
                const bf16x8 vf = *reinterpret_cast<const bf16x8*>(
                    &V_lds[d * 64 + (((ks * 4 + lhi) ^ sw) << 3)]);
                o[cg] = __builtin_amdgcn_mfma_f32_16x16x32_bf16(pa[ks], vf, o[cg], 0, 0, 0);
            }
        }
        // ---- l += P . ones  (row-sum in D layout; replaces shuffle reduce) ----
        #pragma unroll
        for (int ks = 0; ks < 2; ++ks)
            lacc = __builtin_amdgcn_mfma_f32_16x16x32_bf16(pa[ks], ones8, lacc, 0, 0, 0);

        __syncthreads();
    }

    // ---- epilogue: normalize, write bf16 in (b,s,h*HD+d) layout ----
    #pragma unroll
    for (int j = 0; j < 4; ++j) {
        const float inv = 1.f / lacc[j];
        const int qg = q0 + w * 16 + lhi * 4 + j;
        short* op = out + (size_t)(b * SEQ + qg) * DIM + h * HD;
        #pragma unroll
        for (int cg = 0; cg < 8; ++cg)
            op[cg * 16 + lr] = f2bf(o[cg][j] * inv);
    }
}

// ---------------------------------------------------------------------------
// Launch
// ---------------------------------------------------------------------------
extern "C" void kernel_launch(void* const* d_in, const int* in_sizes, int n_in,
                              void* d_out, int out_size, void* d_ws, size_t ws_size,
                              hipStream_t stream) {
    const float* x      = (const float*)d_in[0];
    const float* W_qkv  = (const float*)d_in[1];
    const float* b_qkv  = (const float*)d_in[2];
    const float* W_proj = (const float*)d_in[3];
    const float* b_proj = (const float*)d_in[4];
    // d_in[5] = mask: causal, applied analytically.

    float* out = (float*)d_out;

    // ws layout (bf16 shorts): qkv 48MiB | attn_out 16MiB | x 16MiB | WqkvT 24MiB | WprojT 8MiB
    short* qkv_bf  = (short*)d_ws;
    short* attn_bf = qkv_bf  + (size_t)TOKENS * QKV_N;
    short* x_bf    = attn_bf + (size_t)TOKENS * DIM;
    short* wqkv_t  = x_bf    + (size_t)TOKENS * DIM;
    short* wproj_t = wqkv_t  + (size_t)DIM * QKV_N;

    // 0) casts / transposes
    f32_to_bf16_kernel<<<TOKENS * DIM / (256 * 8), 256, 0, stream>>>(x, x_bf);
    {
        dim3 g(QKV_N / 64, DIM / 64);
        transpose_f32_to_bf16<<<g, 256, 0, stream>>>(W_qkv, wqkv_t, DIM, QKV_N);
    }
    {
        dim3 g(DIM / 64, DIM / 64);
        transpose_f32_to_bf16<<<g, 256, 0, stream>>>(W_proj, wproj_t, DIM, DIM);
    }

    // 1) qkv = x @ W_qkv + b_qkv  (bf16 MFMA, bf16 out)
    {
        const int nM = TOKENS / 128, nN = QKV_N / 128;   // 32 x 48 = 1536
        gemm_mfma_kernel<true><<<nM * nN, 256, 0, stream>>>(
            x_bf, wqkv_t, b_qkv, (void*)qkv_bf, TOKENS, QKV_N, DIM, nM);
    }
    // 2) causal MFMA flash attention -> bf16 [4096][2048]
    attn_mfma_kernel<<<BATCH * NH * (SEQ / 64), 256, 0, stream>>>(qkv_bf, attn_bf);

    // 3) out = attn_out @ W_proj + b_proj  (bf16 MFMA, fp32 out)
    {
        const int nM = TOKENS / 128, nN = DIM / 128;     // 32 x 16 = 512
        gemm_mfma_kernel<false><<<nM * nN, 256, 0, stream>>>(
            attn_bf, wproj_t, b_proj, (void*)out, TOKENS, DIM, DIM, nM);
    }
}

// Round 15
// 247.625 us; speedup vs baseline: 1.1293x; 1.1293x over previous
//
#include <hip/hip_runtime.h>
#include <hip/hip_bf16.h>
#include <math.h>

// Problem constants (reference: B=2, S=2048, D=2048, H=16, HD=128)
#define BATCH 2
#define SEQ   2048
#define DIM   2048
#define NH    16
#define HD    128
#define QKV_N (3 * DIM)       // 6144
#define TOKENS (BATCH * SEQ)  // 4096

typedef __attribute__((ext_vector_type(8))) short bf16x8;
typedef __attribute__((ext_vector_type(4))) float f32x4;

typedef __attribute__((address_space(1))) const void* as1cv;
typedef __attribute__((address_space(3))) void* as3v;

__device__ __forceinline__ short f2bf(float x) {
    unsigned u = __float_as_uint(x);
    u += 0x7fffu + ((u >> 16) & 1u);   // round-to-nearest-even (finite inputs)
    return (short)(u >> 16);
}

__device__ __forceinline__ float bf2f(short x) {
    return __uint_as_float(((unsigned)(unsigned short)x) << 16);
}

__device__ __forceinline__ void gload16(const short* g, short* lds) {
    // 16B per lane; LDS dest = wave-uniform base + lane*16 (HW). Source is per-lane.
    __builtin_amdgcn_global_load_lds((as1cv)g, (as3v)lds, 16, 0, 0);
}

// ---------------------------------------------------------------------------
// fp32 -> bf16 elementwise cast (x). Exact-cover grid, 8 elems/thread.
// ---------------------------------------------------------------------------
__global__ __launch_bounds__(256)
void f32_to_bf16_kernel(const float* __restrict__ in, short* __restrict__ out) {
    const size_t i = ((size_t)blockIdx.x * 256 + threadIdx.x) * 8;
    const float4 a = *reinterpret_cast<const float4*>(in + i);
    const float4 b = *reinterpret_cast<const float4*>(in + i + 4);
    bf16x8 v;
    v[0] = f2bf(a.x); v[1] = f2bf(a.y); v[2] = f2bf(a.z); v[3] = f2bf(a.w);
    v[4] = f2bf(b.x); v[5] = f2bf(b.y); v[6] = f2bf(b.z); v[7] = f2bf(b.w);
    *reinterpret_cast<bf16x8*>(out + i) = v;
}

// ---------------------------------------------------------------------------
// fp32 [K][N] -> bf16 [N][K] tiled transpose+cast (weights).
// ---------------------------------------------------------------------------
__global__ __launch_bounds__(256)
void transpose_f32_to_bf16(const float* __restrict__ W, short* __restrict__ Wt,
                           int K, int N) {
    __shared__ float t[64][65];
    const int tid = threadIdx.x;
    const int n0 = blockIdx.x * 64;
    const int k0 = blockIdx.y * 64;
    const int tc = tid & 63, tr = tid >> 6;
    #pragma unroll
    for (int i = 0; i < 16; ++i)
        t[tr + i * 4][tc] = W[(size_t)(k0 + tr + i * 4) * N + n0 + tc];
    __syncthreads();
    #pragma unroll
    for (int i = 0; i < 16; ++i)
        Wt[(size_t)(n0 + tr + i * 4) * K + k0 + tc] = f2bf(t[tc][tr + i * 4]);
}

// ---------------------------------------------------------------------------
// bf16 MFMA GEMM: C[M,N] = A[M,K] @ Bt[N,K]^T + bias[N]
// 128x128 tile, BK=64, 256 threads / 4 waves, double-buffered with counted
// vmcnt(8) (T4) + setprio (T5). ROUND-4 SCHEDULE (proven 117us QKV):
// reads -> lgkm drain -> barrier -> STAGE(t+2) [issues BEFORE the MFMA
// cluster so HBM latency hides under the matrix pipe -- r13 showed moving
// STAGE after MFMA costs 20%] -> setprio'd MFMA -> counted vmcnt(8) -> barrier.
// ---------------------------------------------------------------------------
template <bool BF16OUT>
__global__ __launch_bounds__(256, 2)
void gemm_mfma_kernel(const short* __restrict__ A, const short* __restrict__ Bt,
                      const float* __restrict__ bias, void* __restrict__ Cv,
                      int M, int N, int K, int nM) {
    __shared__ short A_lds[2][128 * 64];   // 2 x 16 KiB
    __shared__ short B_lds[2][128 * 64];   // 2 x 16 KiB

    const int tid  = threadIdx.x;
    const int lane = tid & 63;
    const int w    = tid >> 6;
    const int lr   = lane & 15;
    const int lhi  = lane >> 4;
    const int wr   = w >> 1;
    const int wc   = w & 1;

    const int nwg  = gridDim.x;
    const int cpx  = nwg >> 3;
    const int orig = blockIdx.x;
    const int wg   = (orig & 7) * cpx + (orig >> 3);
    const int bm   = (wg % nM) * 128;
    const int bn   = (wg / nM) * 128;

    const int srow   = tid >> 3;                   // 0..31
    const int schunk = (tid & 7) ^ (srow & 7);     // inverse-swizzled source chunk
    const short* gA = A  + (size_t)(bm + srow) * K + schunk * 8;
    const short* gB = Bt + (size_t)(bn + srow) * K + schunk * 8;

    const int nt = K >> 6;                         // 32 for K=2048

    auto STAGE = [&](int t, int buf) {
        const int ko = t * 64;
        short* la = &A_lds[buf][w * 512];
        short* lb = &B_lds[buf][w * 512];
        #pragma unroll
        for (int i = 0; i < 4; ++i)
            gload16(gA + (size_t)(i * 32) * K + ko, la + i * 2048);
        #pragma unroll
        for (int i = 0; i < 4; ++i)
            gload16(gB + (size_t)(i * 32) * K + ko, lb + i * 2048);
    };

    f32x4 acc[4][4] = {};

    STAGE(0, 0);
    STAGE(1, 1);
    asm volatile("s_waitcnt vmcnt(8)" ::: "memory");   // tile 0 landed
    __builtin_amdgcn_s_barrier();

    int cur = 0;
    for (int t = 0; t < nt; ++t, cur ^= 1) {
        bf16x8 af[2][4], bfr[2][4];
        const short* Ab = &A_lds[cur][0];
        const short* Bb = &B_lds[cur][0];
        #pragma unroll
        for (int ks = 0; ks < 2; ++ks) {
            const int cb = ks * 4 + lhi;
            #pragma unroll
            for (int mi = 0; mi < 4; ++mi) {
                const int r = wr * 64 + mi * 16 + lr;
                af[ks][mi] = *reinterpret_cast<const bf16x8*>(
                    &Ab[r * 64 + ((cb ^ (r & 7)) << 3)]);
            }
            #pragma unroll
            for (int ni = 0; ni < 4; ++ni) {
                const int c = wc * 64 + ni * 16 + lr;
                bfr[ks][ni] = *reinterpret_cast<const bf16x8*>(
                    &Bb[c * 64 + ((cb ^ (c & 7)) << 3)]);
            }
        }
        asm volatile("s_waitcnt lgkmcnt(0)" ::: "memory");
        __builtin_amdgcn_sched_barrier(0);
        __builtin_amdgcn_s_barrier();          // all waves done reading buf[cur]
        __builtin_amdgcn_sched_barrier(0);

        if (t + 2 < nt) STAGE(t + 2, cur);     // overwrite the buffer just read

        __builtin_amdgcn_s_setprio(1);
        #pragma unroll
        for (int ks = 0; ks < 2; ++ks)
            #pragma unroll
            for (int mi = 0; mi < 4; ++mi)
                #pragma unroll
                for (int ni = 0; ni < 4; ++ni)
                    acc[mi][ni] = __builtin_amdgcn_mfma_f32_16x16x32_bf16(
                        af[ks][mi], bfr[ks][ni], acc[mi][ni], 0, 0, 0);
        __builtin_amdgcn_s_setprio(0);
        __builtin_amdgcn_sched_barrier(0);

        if (t + 2 < nt) {
            asm volatile("s_waitcnt vmcnt(8)" ::: "memory");   // t+1 landed
            __builtin_amdgcn_s_barrier();
        } else if (t + 1 < nt) {
            asm volatile("s_waitcnt vmcnt(0)" ::: "memory");   // last tile landed
            __builtin_amdgcn_s_barrier();
        }
    }

    #pragma unroll
    for (int mi = 0; mi < 4; ++mi) {
        #pragma unroll
        for (int j = 0; j < 4; ++j) {
            const int r = bm + wr * 64 + mi * 16 + lhi * 4 + j;
            #pragma unroll
            for (int ni = 0; ni < 4; ++ni) {
                const int c = bn + wc * 64 + ni * 16 + lr;
                const float v = acc[mi][ni][j] + bias[c];
                if (BF16OUT) ((short*)Cv)[(size_t)r * N + c] = f2bf(v);
                else         ((float*)Cv)[(size_t)r * N + c] = v;
            }
        }
    }
}

// ---------------------------------------------------------------------------
// MFMA flash attention (bf16 in/out, fp32 accum). Round-11 proven version:
// 1024 blocks / 4 waves, gload_lds K, pair-packed V, no-max fused softmax
// (log2-domain prescale, exp2, ones-MFMA row-sum; fused live ranges keep
// VGPR <= 128).
// ---------------------------------------------------------------------------
__device__ __forceinline__ int swz8(int row) {   // units: shorts (8 = 16B chunk)
    return ((row ^ (row >> 2)) & 7) << 3;
}

__global__ __launch_bounds__(256)
void attn_mfma_kernel(const short* __restrict__ qkv, short* __restrict__ out) {
    __shared__ short K_lds[64 * 128];    // 16 KiB
    __shared__ short V_lds[128 * 64];    // 16 KiB  (d-major, pair-packed chunks)
    __shared__ short P_lds[4 * 16 * 64]; // 8 KiB   (per-wave P tile)

    const int tid  = threadIdx.x;
    const int lane = tid & 63;
    const int w    = tid >> 6;

    const int z    = blockIdx.x;                 // 0..1023
    const int qblk = (SEQ / 64 - 1) - (z >> 5);  // descending for load balance
    const int bh   = z & 31;
    const int h    = bh & 15;
    const int b    = bh >> 4;

    const int q0 = qblk * 64;
    const size_t tokbase = (size_t)b * SEQ * QKV_N;

    const int lr  = lane & 15;
    const int lhi = lane >> 4;
    // (1/sqrt(128)) * log2(e): QK^T lands in log2 domain, exp2f is 1 instr
    const float lg2scale = 0.1275174468658922f;

    // Q fragments, pre-scaled
    const int qrow = q0 + w * 16 + lr;
    const short* qrowp = qkv + tokbase + (size_t)qrow * QKV_N + h * HD;
    bf16x8 qfrag[4];
    #pragma unroll
    for (int ks = 0; ks < 4; ++ks) {
        bf16x8 v = *reinterpret_cast<const bf16x8*>(qrowp + ks * 32 + lhi * 8);
        bf16x8 sv;
        #pragma unroll
        for (int e = 0; e < 8; ++e) sv[e] = f2bf(bf2f(v[e]) * lg2scale);
        qfrag[ks] = sv;
    }

    // ones B-fragment for the P row-sum MFMA
    bf16x8 ones8;
    #pragma unroll
    for (int e = 0; e < 8; ++e) ones8[e] = (short)0x3F80;   // bf16 1.0

    f32x4 o[8] = {};
    f32x4 lacc = {};                 // l[j] accumulated via ones-MFMA

    const int wq0 = q0 + w * 16;
    const int ntiles = qblk + 1;

    // K staging map: issue i covers rows [i*16, i*16+16)
    const int krow16 = tid >> 4;                 // 0..15 (row within issue group)
    const int kch    = tid & 15;                 // stored 16B chunk 0..15

    for (int t = 0; t < ntiles; ++t) {
        // ---- stage K via global_load_lds (pre-swizzled source, linear dest) ----
        {
            const short* kb = qkv + tokbase + (size_t)(t * 64) * QKV_N + DIM + h * HD;
            #pragma unroll
            for (int i = 0; i < 4; ++i) {
                const int row = i * 16 + krow16;
                const int sch = (kch & 8) | ((kch & 7) ^ ((row ^ (row >> 2)) & 7));
                gload16(kb + (size_t)row * QKV_N + sch * 8,
                        &K_lds[(i * 16 + w * 4) * 128]);
            }
        }
        // ---- stage V (pair-packed b32 scatter, chunk-swizzled) ----
        {
            const int p  = tid >> 3;            // kv pair index 0..31
            const int c  = tid & 7;             // d chunk (16 d each)
            const int kv = p * 2;
            const int kc = kv >> 3;             // kv chunk, per-thread const
            const short* vrow = qkv + tokbase + (size_t)(t * 64 + kv) * QKV_N
                                + 2 * DIM + h * HD + c * 16;
            #pragma unroll
            for (int half = 0; half < 2; ++half) {
                const bf16x8 va = *reinterpret_cast<const bf16x8*>(vrow + half * 8);
                const bf16x8 vb = *reinterpret_cast<const bf16x8*>(vrow + QKV_N + half * 8);
                #pragma unroll
                for (int dd = 0; dd < 8; ++dd) {
                    const int d  = c * 16 + half * 8 + dd;
                    const int sw = ((d >> 4) ^ d) & 7;
                    const unsigned pk = ((unsigned)(unsigned short)va[dd]) |
                                        (((unsigned)(unsigned short)vb[dd]) << 16);
                    *reinterpret_cast<unsigned*>(
                        &V_lds[d * 64 + ((kc ^ sw) << 3) + (kv & 7)]) = pk;
                }
            }
        }
        __syncthreads();   // drains vmcnt (gload_lds) + lgkm; tile visible

        // ---- QK^T (pre-scaled, log2 domain): S[16][64] ----
        f32x4 s[4] = {};
        #pragma unroll
        for (int ks = 0; ks < 4; ++ks) {
            #pragma unroll
            for (int cg = 0; cg < 4; ++cg) {
                const int row = cg * 16 + lr;
                const bf16x8 kf = *reinterpret_cast<const bf16x8*>(
                    &K_lds[row * 128 + ((ks * 32 + lhi * 8) ^ swz8(row))]);
                s[cg] = __builtin_amdgcn_mfma_f32_16x16x32_bf16(qfrag[ks], kf, s[cg], 0, 0, 0);
            }
        }

        // ---- FUSED mask + exp2 + pack (no max, no shuffles; s dies in-loop) ----
        const bool dmask = (t == qblk);
        short* pbase = &P_lds[w * 1024];
        #pragma unroll
        for (int cg = 0; cg < 4; ++cg) {
            const int kvg = t * 64 + cg * 16 + lr;
            const int cx  = cg * 16 + lr;
            #pragma unroll
            for (int j = 0; j < 4; ++j) {
                float sv = s[cg][j];
                if (dmask && (kvg > wq0 + lhi * 4 + j)) sv = -1.0e38f;
                sv = exp2f(fminf(sv, 80.f));
                const int rw = lhi * 4 + j;
                pbase[rw * 64 + (cx ^ swz8(rw))] = f2bf(sv);
            }
        }
        bf16x8 pa[2];
        #pragma unroll
        for (int ks = 0; ks < 2; ++ks)
            pa[ks] = *reinterpret_cast<const bf16x8*>(
                &pbase[lr * 64 + ((ks * 32 + lhi * 8) ^ swz8(lr))]);

        // ---- PV: O[16][128] += P[16][64] . V[64][128] ----
        #pragma unroll
        for (int cg = 0; cg < 8; ++cg) {
            const int d  = cg * 16 + lr;
            const int sw = ((d >> 4) ^ d) & 7;
            #pragma unroll
            for (int ks = 0; ks < 2; ++ks) {
                const bf16x8 vf = *reinterpret_cast<const bf16x8*>(
                    &V_lds[d * 64 + (((ks * 4 + lhi) ^ sw) << 3)]);
                o[cg] = __builtin_amdgcn_mfma_f32_16x16x32_bf16(pa[ks], vf, o[cg], 0, 0, 0);
            }
        }
        // ---- l += P . ones  (row-sum in D layout; replaces shuffle reduce) ----
        #pragma unroll
        for (int ks = 0; ks < 2; ++ks)
            lacc = __builtin_amdgcn_mfma_f32_16x16x32_bf16(pa[ks], ones8, lacc, 0, 0, 0);

        __syncthreads();
    }

    // ---- epilogue: normalize, write bf16 in (b,s,h*HD+d) layout ----
    #pragma unroll
    for (int j = 0; j < 4; ++j) {
        const float inv = 1.f / lacc[j];
        const int qg = q0 + w * 16 + lhi * 4 + j;
        short* op = out + (size_t)(b * SEQ + qg) * DIM + h * HD;
        #pragma unroll
        for (int cg = 0; cg < 8; ++cg)
            op[cg * 16 + lr] = f2bf(o[cg][j] * inv);
    }
}

// ---------------------------------------------------------------------------
// Launch
// ---------------------------------------------------------------------------
extern "C" void kernel_launch(void* const* d_in, const int* in_sizes, int n_in,
                              void* d_out, int out_size, void* d_ws, size_t ws_size,
                              hipStream_t stream) {
    const float* x      = (const float*)d_in[0];
    const float* W_qkv  = (const float*)d_in[1];
    const float* b_qkv  = (const float*)d_in[2];
    const float* W_proj = (const float*)d_in[3];
    const float* b_proj = (const float*)d_in[4];
    // d_in[5] = mask: causal, applied analytically.

    float* out = (float*)d_out;

    // ws layout (bf16 shorts): qkv 48MiB | attn_out 16MiB | x 16MiB | WqkvT 24MiB | WprojT 8MiB
    short* qkv_bf  = (short*)d_ws;
    short* attn_bf = qkv_bf  + (size_t)TOKENS * QKV_N;
    short* x_bf    = attn_bf + (size_t)TOKENS * DIM;
    short* wqkv_t  = x_bf    + (size_t)TOKENS * DIM;
    short* wproj_t = wqkv_t  + (size_t)DIM * QKV_N;

    // 0) casts / transposes
    f32_to_bf16_kernel<<<TOKENS * DIM / (256 * 8), 256, 0, stream>>>(x, x_bf);
    {
        dim3 g(QKV_N / 64, DIM / 64);
        transpose_f32_to_bf16<<<g, 256, 0, stream>>>(W_qkv, wqkv_t, DIM, QKV_N);
    }
    {
        dim3 g(DIM / 64, DIM / 64);
        transpose_f32_to_bf16<<<g, 256, 0, stream>>>(W_proj, wproj_t, DIM, DIM);
    }

    // 1) qkv = x @ W_qkv + b_qkv  (bf16 MFMA, bf16 out)
    {
        const int nM = TOKENS / 128, nN = QKV_N / 128;   // 32 x 48 = 1536
        gemm_mfma_kernel<true><<<nM * nN, 256, 0, stream>>>(
            x_bf, wqkv_t, b_qkv, (void*)qkv_bf, TOKENS, QKV_N, DIM, nM);
    }
    // 2) causal MFMA flash attention -> bf16 [4096][2048]
    attn_mfma_kernel<<<BATCH * NH * (SEQ / 64), 256, 0, stream>>>(qkv_bf, attn_bf);

    // 3) out = attn_out @ W_proj + b_proj  (bf16 MFMA, fp32 out)
    {
        const int nM = TOKENS / 128, nN = DIM / 128;     // 32 x 16 = 512
        gemm_mfma_kernel<false><<<nM * nN, 256, 0, stream>>>(
            attn_bf, wproj_t, b_proj, (void*)out, TOKENS, DIM, DIM, nM);
    }
}